// Round 1
// baseline (1206.592 us; speedup 1.0000x reference)
//
#include <hip/hip_runtime.h>

// Problem constants (from reference)
#define N_A 100000
#define N_B 60000
#define N_C 40000
#define NTOT 200000   // N_A + N_B + N_C
#define NEDGE 3200000
#define D 64

// ---------------------------------------------------------------------------
// Fused per-type encoder + GCN linear:
//   enc  = relu(feat @ W + b)        (K = 512/256/128, D = 64)
//   supp = enc @ gcn_W + gcn_b       (written to global support buffer)
// Block: 256 threads, 32 nodes per block. Thread owns 4 nodes x 2 dims.
// LDS: sW (64x64 W chunk, reused for gcn_W), sF (32x64 feat chunk),
//      sE (32x64 enc tile). 32 KB total -> 5 blocks/CU by LDS.
// ---------------------------------------------------------------------------

__device__ __forceinline__ void tile_mm64(const float* __restrict__ sA,
                                          const float* __restrict__ sW,
                                          const int nidx[4], int d0,
                                          float acc[4][2])
{
#pragma unroll
    for (int kk = 0; kk < 64; kk += 4) {
        float wl[4], wh[4];
#pragma unroll
        for (int u = 0; u < 4; ++u) {
            wl[u] = sW[(kk + u) * 64 + d0];        // ds_read2 candidates
            wh[u] = sW[(kk + u) * 64 + d0 + 32];
        }
#pragma unroll
        for (int j = 0; j < 4; ++j) {
            const float4 f = *(const float4*)(sA + nidx[j] * 64 + kk); // broadcast b128
            acc[j][0] = fmaf(f.x, wl[0], acc[j][0]);
            acc[j][0] = fmaf(f.y, wl[1], acc[j][0]);
            acc[j][0] = fmaf(f.z, wl[2], acc[j][0]);
            acc[j][0] = fmaf(f.w, wl[3], acc[j][0]);
            acc[j][1] = fmaf(f.x, wh[0], acc[j][1]);
            acc[j][1] = fmaf(f.y, wh[1], acc[j][1]);
            acc[j][1] = fmaf(f.z, wh[2], acc[j][1]);
            acc[j][1] = fmaf(f.w, wh[3], acc[j][1]);
        }
    }
}

template <int K>
__global__ __launch_bounds__(256) void enc_gcn_kernel(
    const float* __restrict__ feat, const float* __restrict__ W,
    const float* __restrict__ bias, const float* __restrict__ gW,
    const float* __restrict__ gb, float* __restrict__ support, int node0)
{
    __shared__ float sW[64 * 64];   // W chunk, then gcn_W
    __shared__ float sF[32 * 64];   // feat chunk [node][k]
    __shared__ float sE[32 * 64];   // relu(enc) tile [node][d]

    const int tid = threadIdx.x;
    const int d0  = tid & 31;        // dims d0 and d0+32
    const int h   = (tid >> 5) & 1;  // node parity within wave
    const int w   = tid >> 6;        // wave id 0..3
    const int blockNode = blockIdx.x * 32;

    int nidx[4];
#pragma unroll
    for (int j = 0; j < 4; ++j) nidx[j] = j * 8 + w * 2 + h;

    float acc[4][2] = {};

    for (int k0 = 0; k0 < K; k0 += 64) {
        // stage W chunk [64 k][64 d], coalesced
#pragma unroll
        for (int i = 0; i < 16; ++i) {
            int idx = i * 256 + tid;
            sW[idx] = W[(long long)(k0 + (idx >> 6)) * 64 + (idx & 63)];
        }
        // stage feat chunk [32 n][64 k], coalesced
#pragma unroll
        for (int i = 0; i < 8; ++i) {
            int idx = i * 256 + tid;
            sF[idx] = feat[(long long)(blockNode + (idx >> 6)) * K + k0 + (idx & 63)];
        }
        __syncthreads();
        tile_mm64(sF, sW, nidx, d0, acc);
        __syncthreads();  // before next chunk overwrites sW/sF
    }

    // bias + ReLU -> sE
    {
        const float b0 = bias[d0], b1 = bias[d0 + 32];
#pragma unroll
        for (int j = 0; j < 4; ++j) {
            sE[nidx[j] * 64 + d0]      = fmaxf(acc[j][0] + b0, 0.f);
            sE[nidx[j] * 64 + d0 + 32] = fmaxf(acc[j][1] + b1, 0.f);
        }
    }
    // stage gcn_W into sW (compute of phase 1 already fenced above)
#pragma unroll
    for (int i = 0; i < 16; ++i) {
        int idx = i * 256 + tid;
        sW[idx] = gW[idx];
    }
    __syncthreads();

    float a2[4][2] = {};
    tile_mm64(sE, sW, nidx, d0, a2);

    const float g0 = gb[d0], g1 = gb[d0 + 32];
#pragma unroll
    for (int j = 0; j < 4; ++j) {
        const long long row = (long long)(node0 + blockNode + nidx[j]);
        support[row * 64 + d0]      = a2[j][0] + g0;
        support[row * 64 + d0 + 32] = a2[j][1] + g1;
    }
}

// ---------------------------------------------------------------------------
// Zero the accumulator (harness poisons d_out with 0xAA before every launch)
// ---------------------------------------------------------------------------
__global__ void zero_kernel(float4* __restrict__ p, long long n4)
{
    long long i  = (long long)blockIdx.x * blockDim.x + threadIdx.x;
    long long st = (long long)gridDim.x * blockDim.x;
    for (; i < n4; i += st) p[i] = float4{0.f, 0.f, 0.f, 0.f};
}

// ---------------------------------------------------------------------------
// Edge scatter: out[dst][d] += support[src][d] * w[e]
// One 64-lane group per edge, lane d owns dim d. Device-scope fp32 atomics.
// ---------------------------------------------------------------------------
__global__ void scatter_kernel(const float* __restrict__ support,
                               const float* __restrict__ ew,
                               const int* __restrict__ esrc,
                               const int* __restrict__ edst,
                               float* __restrict__ out, int E)
{
    const int d  = threadIdx.x & 63;
    int gw       = blockIdx.x * (blockDim.x >> 6) + (threadIdx.x >> 6);
    const int nw = gridDim.x * (blockDim.x >> 6);
    for (int e = gw; e < E; e += nw) {
        const int   s = esrc[e];
        const int   t = edst[e];
        const float we = ew[e];
        const float v = support[(long long)s * 64 + d] * we;
        atomicAdd(&out[(long long)t * 64 + d], v);   // fire-and-forget
    }
}

// ---------------------------------------------------------------------------
// Row L2-normalize in place: one 64-lane group per row
// ---------------------------------------------------------------------------
__global__ void normalize_kernel(float* __restrict__ out, int N)
{
    const int d   = threadIdx.x & 63;
    const int row = blockIdx.x * (blockDim.x >> 6) + (threadIdx.x >> 6);
    if (row < N) {
        const long long base = (long long)row * 64;
        float x  = out[base + d];
        float ss = x * x;
#pragma unroll
        for (int o = 32; o; o >>= 1) ss += __shfl_xor(ss, o, 64);
        const float nrm = fmaxf(sqrtf(ss), 1e-12f);
        out[base + d] = x / nrm;
    }
}

extern "C" void kernel_launch(void* const* d_in, const int* in_sizes, int n_in,
                              void* d_out, int out_size, void* d_ws, size_t ws_size,
                              hipStream_t stream)
{
    const float* feat_a = (const float*)d_in[0];
    const float* W_a    = (const float*)d_in[1];
    const float* b_a    = (const float*)d_in[2];
    const float* feat_b = (const float*)d_in[3];
    const float* W_b    = (const float*)d_in[4];
    const float* b_b    = (const float*)d_in[5];
    const float* feat_c = (const float*)d_in[6];
    const float* W_c    = (const float*)d_in[7];
    const float* b_c    = (const float*)d_in[8];
    const float* gcn_W  = (const float*)d_in[9];
    const float* gcn_b  = (const float*)d_in[10];
    const float* ew     = (const float*)d_in[11];
    const int*   esrc   = (const int*)d_in[12];
    const int*   edst   = (const int*)d_in[13];

    float* out     = (float*)d_out;
    float* support = (float*)d_ws;   // needs NTOT*64*4 = 51.2 MB of workspace

    // zero the segment-sum accumulator (d_out is poisoned before each launch)
    zero_kernel<<<2048, 256, 0, stream>>>((float4*)out, (long long)NTOT * D / 4);

    // fused encoder + GCN linear per node type
    enc_gcn_kernel<512><<<N_A / 32, 256, 0, stream>>>(feat_a, W_a, b_a, gcn_W, gcn_b, support, 0);
    enc_gcn_kernel<256><<<N_B / 32, 256, 0, stream>>>(feat_b, W_b, b_b, gcn_W, gcn_b, support, N_A);
    enc_gcn_kernel<128><<<N_C / 32, 256, 0, stream>>>(feat_c, W_c, b_c, gcn_W, gcn_b, support, N_A + N_B);

    // edge scatter with fp32 atomics
    scatter_kernel<<<8192, 256, 0, stream>>>(support, ew, esrc, edst, out, NEDGE);

    // row-wise L2 normalize
    normalize_kernel<<<NTOT / 4, 256, 0, stream>>>(out, NTOT);
}

// Round 2
// 1042.144 us; speedup vs baseline: 1.1578x; 1.1578x over previous
//
#include <hip/hip_runtime.h>

// Problem constants (from reference)
#define N_A 100000
#define N_B 60000
#define N_C 40000
#define NTOT 200000   // N_A + N_B + N_C
#define NEDGE 3200000
#define D 64

#define SCAN_BLK 1024
#define NB_SCAN ((NTOT + SCAN_BLK - 1) / SCAN_BLK)   // 196

// ---------------------------------------------------------------------------
// Fused per-type encoder + GCN linear (unchanged from R0):
//   enc  = relu(feat @ W + b);  supp = enc @ gcn_W + gcn_b
// ---------------------------------------------------------------------------
__device__ __forceinline__ void tile_mm64(const float* __restrict__ sA,
                                          const float* __restrict__ sW,
                                          const int nidx[4], int d0,
                                          float acc[4][2])
{
#pragma unroll
    for (int kk = 0; kk < 64; kk += 4) {
        float wl[4], wh[4];
#pragma unroll
        for (int u = 0; u < 4; ++u) {
            wl[u] = sW[(kk + u) * 64 + d0];
            wh[u] = sW[(kk + u) * 64 + d0 + 32];
        }
#pragma unroll
        for (int j = 0; j < 4; ++j) {
            const float4 f = *(const float4*)(sA + nidx[j] * 64 + kk);
            acc[j][0] = fmaf(f.x, wl[0], acc[j][0]);
            acc[j][0] = fmaf(f.y, wl[1], acc[j][0]);
            acc[j][0] = fmaf(f.z, wl[2], acc[j][0]);
            acc[j][0] = fmaf(f.w, wl[3], acc[j][0]);
            acc[j][1] = fmaf(f.x, wh[0], acc[j][1]);
            acc[j][1] = fmaf(f.y, wh[1], acc[j][1]);
            acc[j][1] = fmaf(f.z, wh[2], acc[j][1]);
            acc[j][1] = fmaf(f.w, wh[3], acc[j][1]);
        }
    }
}

template <int K>
__global__ __launch_bounds__(256) void enc_gcn_kernel(
    const float* __restrict__ feat, const float* __restrict__ W,
    const float* __restrict__ bias, const float* __restrict__ gW,
    const float* __restrict__ gb, float* __restrict__ support, int node0)
{
    __shared__ float sW[64 * 64];
    __shared__ float sF[32 * 64];
    __shared__ float sE[32 * 64];

    const int tid = threadIdx.x;
    const int d0  = tid & 31;
    const int h   = (tid >> 5) & 1;
    const int w   = tid >> 6;
    const int blockNode = blockIdx.x * 32;

    int nidx[4];
#pragma unroll
    for (int j = 0; j < 4; ++j) nidx[j] = j * 8 + w * 2 + h;

    float acc[4][2] = {};

    for (int k0 = 0; k0 < K; k0 += 64) {
#pragma unroll
        for (int i = 0; i < 16; ++i) {
            int idx = i * 256 + tid;
            sW[idx] = W[(long long)(k0 + (idx >> 6)) * 64 + (idx & 63)];
        }
#pragma unroll
        for (int i = 0; i < 8; ++i) {
            int idx = i * 256 + tid;
            sF[idx] = feat[(long long)(blockNode + (idx >> 6)) * K + k0 + (idx & 63)];
        }
        __syncthreads();
        tile_mm64(sF, sW, nidx, d0, acc);
        __syncthreads();
    }

    {
        const float b0 = bias[d0], b1 = bias[d0 + 32];
#pragma unroll
        for (int j = 0; j < 4; ++j) {
            sE[nidx[j] * 64 + d0]      = fmaxf(acc[j][0] + b0, 0.f);
            sE[nidx[j] * 64 + d0 + 32] = fmaxf(acc[j][1] + b1, 0.f);
        }
    }
#pragma unroll
    for (int i = 0; i < 16; ++i) {
        int idx = i * 256 + tid;
        sW[idx] = gW[idx];
    }
    __syncthreads();

    float a2[4][2] = {};
    tile_mm64(sE, sW, nidx, d0, a2);

    const float g0 = gb[d0], g1 = gb[d0 + 32];
#pragma unroll
    for (int j = 0; j < 4; ++j) {
        const long long row = (long long)(node0 + blockNode + nidx[j]);
        support[row * 64 + d0]      = a2[j][0] + g0;
        support[row * 64 + d0 + 32] = a2[j][1] + g1;
    }
}

// ---------------------------------------------------------------------------
// CSR build: zero -> histogram -> 3-pass exclusive scan -> cursor fill
// ---------------------------------------------------------------------------
__global__ void zero_ints(int* __restrict__ p, int n)
{
    int i = blockIdx.x * blockDim.x + threadIdx.x;
    if (i < n) p[i] = 0;
}

__global__ void hist_kernel(const int* __restrict__ edst, int* __restrict__ deg, int e)
{
    int i  = blockIdx.x * blockDim.x + threadIdx.x;
    int st = gridDim.x * blockDim.x;
    for (; i < e; i += st) atomicAdd(&deg[edst[i]], 1);
}

__global__ __launch_bounds__(SCAN_BLK) void s1_blocksums(const int* __restrict__ deg,
                                                         int* __restrict__ partials, int n)
{
    const int tid = threadIdx.x;
    const int i   = blockIdx.x * SCAN_BLK + tid;
    int v = (i < n) ? deg[i] : 0;
#pragma unroll
    for (int o = 32; o; o >>= 1) v += __shfl_xor(v, o, 64);
    __shared__ int wsum[SCAN_BLK / 64];
    if ((tid & 63) == 0) wsum[tid >> 6] = v;
    __syncthreads();
    if (tid == 0) {
        int s = 0;
#pragma unroll
        for (int w = 0; w < SCAN_BLK / 64; ++w) s += wsum[w];
        partials[blockIdx.x] = s;
    }
}

__global__ __launch_bounds__(256) void s2_scan(const int* __restrict__ partials,
                                               int* __restrict__ pscan, int np)
{
    __shared__ int arr[512];
    if (threadIdx.x < np) arr[threadIdx.x] = partials[threadIdx.x];
    __syncthreads();
    if (threadIdx.x == 0) {
        int run = 0;
        for (int i = 0; i < np; ++i) { int t = arr[i]; arr[i] = run; run += t; }
    }
    __syncthreads();
    if (threadIdx.x < np) pscan[threadIdx.x] = arr[threadIdx.x];
}

__global__ __launch_bounds__(SCAN_BLK) void s3_scan(const int* __restrict__ deg,
                                                    const int* __restrict__ pscan,
                                                    int* __restrict__ row_start,
                                                    int* __restrict__ cursor, int n)
{
    const int tid  = threadIdx.x;
    const int lane = tid & 63, wid = tid >> 6;
    const int i    = blockIdx.x * SCAN_BLK + tid;
    int v = (i < n) ? deg[i] : 0;
    int x = v;
#pragma unroll
    for (int o = 1; o < 64; o <<= 1) {
        int y = __shfl_up(x, o, 64);
        if (lane >= o) x += y;
    }
    __shared__ int wsum[SCAN_BLK / 64];
    if (lane == 63) wsum[wid] = x;
    __syncthreads();
    if (tid == 0) {
        int run = 0;
#pragma unroll
        for (int w = 0; w < SCAN_BLK / 64; ++w) { int t = wsum[w]; wsum[w] = run; run += t; }
    }
    __syncthreads();
    if (i < n) {
        const int excl = x - v + wsum[wid] + pscan[blockIdx.x];
        row_start[i] = excl;
        cursor[i]    = excl;
    }
}

__global__ void fill_kernel(const int* __restrict__ esrc, const int* __restrict__ edst,
                            const float* __restrict__ ew, int* __restrict__ cursor,
                            uint2* __restrict__ csr, int e)
{
    int i  = blockIdx.x * blockDim.x + threadIdx.x;
    int st = gridDim.x * blockDim.x;
    for (; i < e; i += st) {
        const int t   = edst[i];
        const int pos = atomicAdd(&cursor[t], 1);
        csr[pos] = make_uint2((unsigned)esrc[i], __float_as_uint(ew[i]));
    }
}

// ---------------------------------------------------------------------------
// Pull-based gather + fused L2 normalize: one 64-lane wave per dst node.
// 4-way unrolled independent gathers hide L2/L3 latency.
// ---------------------------------------------------------------------------
__global__ __launch_bounds__(256) void gather_norm_kernel(const float* __restrict__ support,
                                                          const uint2* __restrict__ csr,
                                                          const int* __restrict__ row_start,
                                                          const int* __restrict__ deg,
                                                          float* __restrict__ out)
{
    const int lane = threadIdx.x & 63;
    const int nid  = blockIdx.x * 4 + (threadIdx.x >> 6);
    if (nid >= NTOT) return;
    const int base = row_start[nid];
    const int dg   = deg[nid];

    float acc = 0.f;
    int i = 0;
    for (; i + 4 <= dg; i += 4) {
        const uint2 c0 = csr[base + i + 0];
        const uint2 c1 = csr[base + i + 1];
        const uint2 c2 = csr[base + i + 2];
        const uint2 c3 = csr[base + i + 3];
        const float v0 = support[(long long)c0.x * D + lane];
        const float v1 = support[(long long)c1.x * D + lane];
        const float v2 = support[(long long)c2.x * D + lane];
        const float v3 = support[(long long)c3.x * D + lane];
        acc = fmaf(v0, __uint_as_float(c0.y), acc);
        acc = fmaf(v1, __uint_as_float(c1.y), acc);
        acc = fmaf(v2, __uint_as_float(c2.y), acc);
        acc = fmaf(v3, __uint_as_float(c3.y), acc);
    }
    for (; i < dg; ++i) {
        const uint2 c = csr[base + i];
        acc = fmaf(support[(long long)c.x * D + lane], __uint_as_float(c.y), acc);
    }

    float ss = acc * acc;
#pragma unroll
    for (int o = 32; o; o >>= 1) ss += __shfl_xor(ss, o, 64);
    const float nrm = fmaxf(sqrtf(ss), 1e-12f);
    out[(long long)nid * D + lane] = acc / nrm;
}

// ---------------------------------------------------------------------------
// Fallback path (R0): zero + atomic scatter + normalize, if ws too small
// ---------------------------------------------------------------------------
__global__ void zero_kernel(float4* __restrict__ p, long long n4)
{
    long long i  = (long long)blockIdx.x * blockDim.x + threadIdx.x;
    long long st = (long long)gridDim.x * blockDim.x;
    for (; i < n4; i += st) p[i] = float4{0.f, 0.f, 0.f, 0.f};
}

__global__ void scatter_kernel(const float* __restrict__ support,
                               const float* __restrict__ ew,
                               const int* __restrict__ esrc,
                               const int* __restrict__ edst,
                               float* __restrict__ out, int E)
{
    const int d  = threadIdx.x & 63;
    int gw       = blockIdx.x * (blockDim.x >> 6) + (threadIdx.x >> 6);
    const int nw = gridDim.x * (blockDim.x >> 6);
    for (int e = gw; e < E; e += nw) {
        const int   s  = esrc[e];
        const int   t  = edst[e];
        const float we = ew[e];
        atomicAdd(&out[(long long)t * 64 + d], support[(long long)s * 64 + d] * we);
    }
}

__global__ void normalize_kernel(float* __restrict__ out, int N)
{
    const int d   = threadIdx.x & 63;
    const int row = blockIdx.x * (blockDim.x >> 6) + (threadIdx.x >> 6);
    if (row < N) {
        const long long base = (long long)row * 64;
        float x  = out[base + d];
        float ss = x * x;
#pragma unroll
        for (int o = 32; o; o >>= 1) ss += __shfl_xor(ss, o, 64);
        const float nrm = fmaxf(sqrtf(ss), 1e-12f);
        out[base + d] = x / nrm;
    }
}

extern "C" void kernel_launch(void* const* d_in, const int* in_sizes, int n_in,
                              void* d_out, int out_size, void* d_ws, size_t ws_size,
                              hipStream_t stream)
{
    const float* feat_a = (const float*)d_in[0];
    const float* W_a    = (const float*)d_in[1];
    const float* b_a    = (const float*)d_in[2];
    const float* feat_b = (const float*)d_in[3];
    const float* W_b    = (const float*)d_in[4];
    const float* b_b    = (const float*)d_in[5];
    const float* feat_c = (const float*)d_in[6];
    const float* W_c    = (const float*)d_in[7];
    const float* b_c    = (const float*)d_in[8];
    const float* gcn_W  = (const float*)d_in[9];
    const float* gcn_b  = (const float*)d_in[10];
    const float* ew     = (const float*)d_in[11];
    const int*   esrc   = (const int*)d_in[12];
    const int*   edst   = (const int*)d_in[13];

    float* out = (float*)d_out;

    // workspace layout (all offsets 256B-aligned)
    char* ws = (char*)d_ws;
    const size_t off_support = 0;                               // 51,200,000 B
    const size_t off_deg     = off_support + (size_t)NTOT * D * 4;
    const size_t off_rowst   = off_deg   + (size_t)NTOT * 4;    // 800,000 B each
    const size_t off_cursor  = off_rowst + (size_t)NTOT * 4;
    const size_t off_part    = off_cursor + (size_t)NTOT * 4;
    const size_t off_pscan   = off_part  + 1024;
    const size_t off_csr     = off_pscan + 1024;
    const size_t need        = off_csr + (size_t)NEDGE * 8;     // ~79.2 MB

    float* support = (float*)(ws + off_support);

    // fused encoder + GCN linear per node type (writes support)
    enc_gcn_kernel<512><<<N_A / 32, 256, 0, stream>>>(feat_a, W_a, b_a, gcn_W, gcn_b, support, 0);
    enc_gcn_kernel<256><<<N_B / 32, 256, 0, stream>>>(feat_b, W_b, b_b, gcn_W, gcn_b, support, N_A);
    enc_gcn_kernel<128><<<N_C / 32, 256, 0, stream>>>(feat_c, W_c, b_c, gcn_W, gcn_b, support, N_A + N_B);

    if (ws_size >= need) {
        int*   deg     = (int*)(ws + off_deg);
        int*   rowst   = (int*)(ws + off_rowst);
        int*   cursor  = (int*)(ws + off_cursor);
        int*   part    = (int*)(ws + off_part);
        int*   pscan   = (int*)(ws + off_pscan);
        uint2* csr     = (uint2*)(ws + off_csr);

        // CSR build (independent of support; same stream)
        zero_ints<<<(NTOT + 255) / 256, 256, 0, stream>>>(deg, NTOT);
        hist_kernel<<<4096, 256, 0, stream>>>(edst, deg, NEDGE);
        s1_blocksums<<<NB_SCAN, SCAN_BLK, 0, stream>>>(deg, part, NTOT);
        s2_scan<<<1, 256, 0, stream>>>(part, pscan, NB_SCAN);
        s3_scan<<<NB_SCAN, SCAN_BLK, 0, stream>>>(deg, pscan, rowst, cursor, NTOT);
        fill_kernel<<<4096, 256, 0, stream>>>(esrc, edst, ew, cursor, csr, NEDGE);

        // pull gather + fused L2 normalize (single write of each out row)
        gather_norm_kernel<<<(NTOT + 3) / 4, 256, 0, stream>>>(support, csr, rowst, deg, out);
    } else {
        // fallback: R0 atomic-scatter path
        zero_kernel<<<2048, 256, 0, stream>>>((float4*)out, (long long)NTOT * D / 4);
        scatter_kernel<<<8192, 256, 0, stream>>>(support, ew, esrc, edst, out, NEDGE);
        normalize_kernel<<<NTOT / 4, 256, 0, stream>>>(out, NTOT);
    }
}